// Round 1
// baseline (155.256 us; speedup 1.0000x reference)
//
#include <hip/hip_runtime.h>

// RoIAlign forward, exact-sampling branch (sampling_ratio=2), aligned=true.
// feat: [4,256,100,100] f32, rois: [512,5] f32 (b,x1,y1,x2,y2), out: [512,256,7,7] f32.

#define FEAT_C 256
#define FEAT_H 100
#define FEAT_W 100
#define NROI   512
#define PHOUT  7
#define PWOUT  7
#define SR     2
#define NBINS  (PHOUT * PWOUT)
#define CG     4                    // channel groups per roi (blocks)
#define CPG    (FEAT_C / CG)        // 64 channels per block
#define SCALE  0.25f

__global__ __launch_bounds__(256) void roialign_fwd(
    const float* __restrict__ feat,
    const float* __restrict__ rois,
    float* __restrict__ out)
{
    // Per-roi sampling geometry, shared across all channels.
    __shared__ int   s_yoff_l[PHOUT * SR];  // y_low * W (clamped)
    __shared__ int   s_yoff_h[PHOUT * SR];  // y_high * W
    __shared__ float s_ly[PHOUT * SR];      // y fractional weight
    __shared__ int   s_xl[PWOUT * SR];
    __shared__ int   s_xh[PWOUT * SR];
    __shared__ float s_lx[PWOUT * SR];
    __shared__ int   s_b;

    const int bid = blockIdx.x;
    const int k   = bid / CG;       // roi index
    const int cg  = bid % CG;       // channel group
    const int tid = threadIdx.x;

    const float* r = rois + k * 5;

    if (tid == 0) s_b = (int)r[0];
    if (tid < PHOUT * SR) {
        // y-axis sample tid = ph*2 + iy
        float sh    = r[2] * SCALE - 0.5f;
        float eh    = r[4] * SCALE - 0.5f;
        float bin_h = (eh - sh) * (1.0f / PHOUT);
        int ph = tid >> 1, iy = tid & 1;
        float y = sh + bin_h * ((float)ph + ((float)iy + 0.5f) * 0.5f);
        y = fmaxf(y, 0.0f);
        int yl = (int)y;            // y >= 0, trunc == floor (matches astype(int32))
        int yh;
        if (yl >= FEAT_H - 1) { yl = FEAT_H - 1; yh = FEAT_H - 1; }
        else                  { yh = yl + 1; }
        s_yoff_l[tid] = yl * FEAT_W;
        s_yoff_h[tid] = yh * FEAT_W;
        s_ly[tid]     = y - (float)yl;
    } else if (tid < 2 * PHOUT * SR) {
        int t = tid - PHOUT * SR;   // x-axis sample t = pw*2 + ix
        float sw    = r[1] * SCALE - 0.5f;
        float ew    = r[3] * SCALE - 0.5f;
        float bin_w = (ew - sw) * (1.0f / PWOUT);
        int pw = t >> 1, ix = t & 1;
        float x = sw + bin_w * ((float)pw + ((float)ix + 0.5f) * 0.5f);
        x = fmaxf(x, 0.0f);
        int xl = (int)x;
        int xh;
        if (xl >= FEAT_W - 1) { xl = FEAT_W - 1; xh = FEAT_W - 1; }
        else                  { xh = xl + 1; }
        s_xl[t] = xl;
        s_xh[t] = xh;
        s_lx[t] = x - (float)xl;
    }
    __syncthreads();

    const int b = s_b;
    const float* fbase = feat + ((size_t)b * FEAT_C + cg * CPG) * (FEAT_H * FEAT_W);
    float*       obase = out  + ((size_t)k * FEAT_C + cg * CPG) * NBINS;

    // i = c_local*49 + bin  ->  obase[i] is fully contiguous (coalesced store).
    for (int i = tid; i < CPG * NBINS; i += 256) {
        int c   = i / NBINS;
        int bin = i - c * NBINS;
        int ph  = bin / PWOUT;
        int pw  = bin - ph * PWOUT;
        const float* f = fbase + c * (FEAT_H * FEAT_W);

        float acc = 0.0f;
        #pragma unroll
        for (int iy = 0; iy < SR; iy++) {
            int   ys  = ph * SR + iy;
            int   yol = s_yoff_l[ys];
            int   yoh = s_yoff_h[ys];
            float ly  = s_ly[ys];
            float hy  = 1.0f - ly;
            #pragma unroll
            for (int ix = 0; ix < SR; ix++) {
                int   xs = pw * SR + ix;
                int   xl = s_xl[xs];
                int   xh = s_xh[xs];
                float lx = s_lx[xs];
                float hx = 1.0f - lx;
                float v1 = f[yol + xl];
                float v2 = f[yol + xh];
                float v3 = f[yoh + xl];
                float v4 = f[yoh + xh];
                acc += hy * (hx * v1 + lx * v2) + ly * (hx * v3 + lx * v4);
            }
        }
        obase[i] = acc * 0.25f;   // / (SR*SR)
    }
}

extern "C" void kernel_launch(void* const* d_in, const int* in_sizes, int n_in,
                              void* d_out, int out_size, void* d_ws, size_t ws_size,
                              hipStream_t stream) {
    const float* feat = (const float*)d_in[0];
    const float* rois = (const float*)d_in[1];
    float*       out  = (float*)d_out;
    roialign_fwd<<<dim3(NROI * CG), dim3(256), 0, stream>>>(feat, rois, out);
}

// Round 2
// 108.879 us; speedup vs baseline: 1.4260x; 1.4260x over previous
//
#include <hip/hip_runtime.h>

// RoIAlign forward (SR=2, aligned). feat [4,256,100,100] f32, rois [512,5], out [512,256,7,7].
// Strategy: per (roi, 8-channel group) block, stage the bilinear source patch
// (<=26x26 per channel, boundary-duplicated) into LDS with coalesced reads,
// then compute all 8*49 outputs from LDS. Removes the scattered-global-gather
// bottleneck of the naive kernel (~32 cy per wave-load from address divergence).

#define FEAT_C 256
#define FEAT_H 100
#define FEAT_W 100
#define HW     (FEAT_H * FEAT_W)
#define NROI   512
#define PHOUT  7
#define PWOUT  7
#define SR     2
#define NBINS  (PHOUT * PWOUT)      // 49
#define CPB    8                    // channels per block
#define GROUPS (FEAT_C / CPB)       // 32 blocks per roi
#define SCALE  0.25f
#define PMAX   26                   // max patch rows/cols (span<=23 +2, margin)
#define PSTR   27                   // patch row stride in dwords (odd: bank spread)
#define CSTR   (PSTR * PMAX)        // per-channel patch stride (702 dwords)

// Sample coordinate -> clamped low index + fractional weight.
// Matches ref: y = max(y,0); yl = floor; yl,yh clamped at H-1; ly = y - yl_clamped.
__device__ __forceinline__ void samp_geo(float s, float binsz, int idx, int sr_i,
                                         int cap, int& lo, float& fr) {
    float v = s + binsz * ((float)idx + ((float)sr_i + 0.5f) * 0.5f);
    v = fmaxf(v, 0.0f);
    int l = (int)v;                 // v>=0: trunc == floor == astype(int32)
    if (l > cap) l = cap;           // == ref's (yl >= H-1 -> H-1)
    fr = v - (float)l;
    lo = l;
}

__global__ __launch_bounds__(256) void roialign_fwd(
    const float* __restrict__ feat,
    const float* __restrict__ rois,
    float* __restrict__ out)
{
    __shared__ float s_patch[CPB * CSTR];       // 22464 B
    __shared__ int2  s_yg[PHOUT * SR];          // {pyl*PSTR, bits(ly)}
    __shared__ int2  s_xg[PWOUT * SR];          // {pxl, bits(lx)}

    const int bid = blockIdx.x;
    const int k   = bid >> 5;                   // roi (GROUPS == 32)
    const int cg  = bid & (GROUPS - 1);
    const int tid = threadIdx.x;

    const float* r = rois + k * 5;
    const int   b  = (int)r[0];
    const float sw = r[1] * SCALE - 0.5f;
    const float sh = r[2] * SCALE - 0.5f;
    const float ew = r[3] * SCALE - 0.5f;
    const float eh = r[4] * SCALE - 0.5f;
    const float bin_h = (eh - sh) * (1.0f / PHOUT);
    const float bin_w = (ew - sw) * (1.0f / PWOUT);

    // Patch bounds: first/last sample lows (identical FP expressions in every
    // thread -> bit-identical, no cross-thread handoff needed).
    int y0, x0, yM, xM; float frd;
    samp_geo(sh, bin_h, 0,         0,      FEAT_H - 1, y0, frd);
    samp_geo(sh, bin_h, PHOUT - 1, SR - 1, FEAT_H - 1, yM, frd);
    samp_geo(sw, bin_w, 0,         0,      FEAT_W - 1, x0, frd);
    samp_geo(sw, bin_w, PWOUT - 1, SR - 1, FEAT_W - 1, xM, frd);
    const int ph_rows = min(yM - y0 + 2, PMAX);   // +1 for high tap (duplicated at border)
    const int pw_cols = min(xM - x0 + 2, PMAX);

    // Geometry (28 threads) — patch-relative offsets + fractional weights.
    if (tid < PHOUT * SR) {
        int lo; float ly;
        samp_geo(sh, bin_h, tid >> 1, tid & 1, FEAT_H - 1, lo, ly);
        s_yg[tid] = make_int2((lo - y0) * PSTR, __float_as_int(ly));
    } else if (tid >= 32 && tid < 32 + PWOUT * SR) {
        int t = tid - 32;
        int lo; float lx;
        samp_geo(sw, bin_w, t >> 1, t & 1, FEAT_W - 1, lo, lx);
        s_xg[t] = make_int2(lo - x0, __float_as_int(lx));
    }

    // Stage patch: rows coalesced along x, 8 rows in parallel, 8 channels inner.
    // Patch col px holds feat col min(x0+px, W-1); same for rows -> the
    // "high" tap is always low+1 in patch space, including at borders.
    const float* fbase = feat + ((size_t)b * FEAT_C + cg * CPB) * HW;
    const int tx   = tid & 31;
    const int trow = tid >> 5;                  // 0..7
    if (tx < pw_cols) {
        int sx = x0 + tx; if (sx > FEAT_W - 1) sx = FEAT_W - 1;
        for (int py = trow; py < ph_rows; py += 8) {
            int sy = y0 + py; if (sy > FEAT_H - 1) sy = FEAT_H - 1;
            const float* fp = fbase + sy * FEAT_W + sx;
            float*       dp = s_patch + py * PSTR + tx;
            #pragma unroll
            for (int c = 0; c < CPB; c++)
                dp[c * CSTR] = fp[c * HW];
        }
    }
    __syncthreads();

    // Compute 8*49 = 392 outputs from LDS; stores fully contiguous.
    float* obase = out + ((size_t)k * FEAT_C + cg * CPB) * NBINS;
    for (int o = tid; o < CPB * NBINS; o += 256) {
        int c   = o / NBINS;
        int bin = o - c * NBINS;
        int ph  = bin / PWOUT;
        int pw  = bin - ph * PWOUT;
        const float* p = s_patch + c * CSTR;

        int2  xg0 = s_xg[pw * 2 + 0];
        int2  xg1 = s_xg[pw * 2 + 1];
        float lx0 = __int_as_float(xg0.y), hx0 = 1.0f - lx0;
        float lx1 = __int_as_float(xg1.y), hx1 = 1.0f - lx1;

        float acc = 0.0f;
        #pragma unroll
        for (int iy = 0; iy < SR; iy++) {
            int2  yg = s_yg[ph * 2 + iy];
            float ly = __int_as_float(yg.y), hy = 1.0f - ly;
            const float* row = p + yg.x;

            const float* q0 = row + xg0.x;      // taps adjacent by construction:
            float v1 = q0[0], v2 = q0[1];       // -> ds_read2_b32 pairs
            float v3 = q0[PSTR], v4 = q0[PSTR + 1];
            acc += hy * (hx0 * v1 + lx0 * v2) + ly * (hx0 * v3 + lx0 * v4);

            const float* q1 = row + xg1.x;
            v1 = q1[0]; v2 = q1[1];
            v3 = q1[PSTR]; v4 = q1[PSTR + 1];
            acc += hy * (hx1 * v1 + lx1 * v2) + ly * (hx1 * v3 + lx1 * v4);
        }
        obase[o] = acc * 0.25f;                 // / (SR*SR)
    }
}

extern "C" void kernel_launch(void* const* d_in, const int* in_sizes, int n_in,
                              void* d_out, int out_size, void* d_ws, size_t ws_size,
                              hipStream_t stream) {
    const float* feat = (const float*)d_in[0];
    const float* rois = (const float*)d_in[1];
    float*       outp = (float*)d_out;
    roialign_fwd<<<dim3(NROI * GROUPS), dim3(256), 0, stream>>>(feat, rois, outp);
}

// Round 3
// 105.374 us; speedup vs baseline: 1.4734x; 1.0333x over previous
//
#include <hip/hip_runtime.h>

// RoIAlign forward (SR=2, aligned). feat [4,256,100,100] f32, rois [512,5], out [512,256,7,7].
// Per (roi, 8-channel) block: stage the bilinear source patch into LDS with
// float4 loads / b128 LDS writes (x-origin aligned down to 4), then compute
// 2 channels per thread with packed-f32 math from LDS.

#define FEAT_C 256
#define FEAT_H 100
#define FEAT_W 100
#define HW     (FEAT_H * FEAT_W)
#define NROI   512
#define PHOUT  7
#define PWOUT  7
#define NBINS  49
#define CPB    8                    // channels per block
#define GROUPS (FEAT_C / CPB)       // 32
#define SCALE  0.25f
#define PROWS  25                   // max patch rows: floor-span<=23 (+2 taps)
#define PSTR   28                   // patch cols (aligned span <=3+23+2=28), %4==0 for b128
#define CSTR   (PSTR * PROWS)       // 700 dwords per channel

typedef float f32x2 __attribute__((ext_vector_type(2)));

// Matches ref: v = max(v,0); l = floor(v); clamp l at cap; fr = v - l_clamped.
__device__ __forceinline__ void samp_geo(float s, float binsz, int idx, int sr_i,
                                         int cap, int& lo, float& fr) {
    float v = s + binsz * ((float)idx + ((float)sr_i + 0.5f) * 0.5f);
    v = fmaxf(v, 0.0f);
    int l = (int)v;
    if (l > cap) l = cap;
    fr = v - (float)l;
    lo = l;
}

__global__ __launch_bounds__(256) void roialign_fwd(
    const float* __restrict__ feat,
    const float* __restrict__ rois,
    float* __restrict__ out)
{
    __shared__ __align__(16) float s_patch[CPB * CSTR];   // 22400 B
    __shared__ __align__(16) int2  s_yg[PHOUT * 2];       // {(yl-y0)*PSTR, bits(ly)}
    __shared__ __align__(16) int2  s_xg[PWOUT * 2];       // {xl-ax0, bits(lx)}
    __shared__ int2 s_bm[NBINS];                          // {ph*2, pw*2}

    const int bid = blockIdx.x;
    const int k   = bid >> 5;
    const int cg  = bid & (GROUPS - 1);
    const int tid = threadIdx.x;

    const float* r = rois + k * 5;
    const int   b  = (int)r[0];
    const float sw = r[1] * SCALE - 0.5f;
    const float sh = r[2] * SCALE - 0.5f;
    const float ew = r[3] * SCALE - 0.5f;
    const float eh = r[4] * SCALE - 0.5f;
    const float bh = (eh - sh) * (1.0f / PHOUT);
    const float bw = (ew - sw) * (1.0f / PWOUT);

    // Patch bounds (bit-identical in every thread).
    int y0, x0, yM, xM; float fd;
    samp_geo(sh, bh, 0,         0, FEAT_H - 1, y0, fd);
    samp_geo(sh, bh, PHOUT - 1, 1, FEAT_H - 1, yM, fd);
    samp_geo(sw, bw, 0,         0, FEAT_W - 1, x0, fd);
    samp_geo(sw, bw, PWOUT - 1, 1, FEAT_W - 1, xM, fd);
    const int  ax0     = x0 & ~3;                         // 16B-aligned x origin
    const int  ph_rows = min(yM - y0 + 2, PROWS);
    const int  aspan   = min(xM - ax0 + 2, PSTR);
    const bool dupx    = (xM >= FEAT_W - 1);              // need col W duplicated

    // Geometry tables (disjoint thread ranges, all before the barrier).
    if (tid < PHOUT * 2) {
        int lo; float fr;
        samp_geo(sh, bh, tid >> 1, tid & 1, FEAT_H - 1, lo, fr);
        s_yg[tid] = make_int2((lo - y0) * PSTR, __float_as_int(fr));
    } else if (tid >= 32 && tid < 32 + PWOUT * 2) {
        int t = tid - 32; int lo; float fr;
        samp_geo(sw, bw, t >> 1, t & 1, FEAT_W - 1, lo, fr);
        s_xg[t] = make_int2(lo - ax0, __float_as_int(fr));
    } else if (tid >= 64 && tid < 64 + NBINS) {
        int bin = tid - 64;
        s_bm[bin] = make_int2((bin / PWOUT) * 2, (bin % PWOUT) * 2);
    }

    // Stage patch: lane = (row py = tid>>3, quad q = tid&7); 8 channels unrolled.
    // One global_load_dwordx4 + one ds_write_b128 per (wave, channel).
    const float* fb = feat + ((size_t)b * FEAT_C + cg * CPB) * HW;
    {
        const int py = tid >> 3;
        const int q  = tid & 7;
        if (py < ph_rows && q * 4 < aspan) {
            int qs = ax0 + q * 4;
            if (qs > FEAT_W - 4) qs = FEAT_W - 4;         // stay in-row; dup col fixed below
            int sy = y0 + py;
            if (sy > FEAT_H - 1) sy = FEAT_H - 1;         // bottom-row duplication
            const float* src = fb + sy * FEAT_W + qs;
            float*       dst = s_patch + py * PSTR + (qs - ax0);
            #pragma unroll
            for (int c = 0; c < CPB; c++)
                *reinterpret_cast<float4*>(dst + c * CSTR) =
                    *reinterpret_cast<const float4*>(src + c * HW);
        }
    }
    __syncthreads();

    if (dupx) {                                           // block-uniform branch
        int c = tid >> 5, py = tid & 31;
        if (py < ph_rows) {
            float* pr = s_patch + c * CSTR + py * PSTR;
            pr[aspan - 1] = pr[aspan - 2];                // duplicate col W-1
        }
    }
    __syncthreads();

    // Compute: thread -> (channel pair cp, bin); 196 threads cover 4*49 = 8ch*49.
    if (tid < 4 * NBINS) {
        const int cp  = tid / NBINS;
        const int bin = tid - cp * NBINS;
        const int2 bm = s_bm[bin];
        const int4 yg = *reinterpret_cast<const int4*>(&s_yg[bm.x]);
        const int4 xg = *reinterpret_cast<const int4*>(&s_xg[bm.y]);
        const float* pA = s_patch + (cp * 2) * CSTR;
        const float* pB = pA + CSTR;

        const float ly0 = __int_as_float(yg.y), hy0 = 1.0f - ly0;
        const float ly1 = __int_as_float(yg.w), hy1 = 1.0f - ly1;
        const float lx0 = __int_as_float(xg.y), hx0 = 1.0f - lx0;
        const float lx1 = __int_as_float(xg.w), hx1 = 1.0f - lx1;

        f32x2 acc = {0.0f, 0.0f};
        auto quad = [&](int ro, float hy, float ly, int xo, float hx, float lx) {
            const float* a = pA + ro + xo;
            const float* q = pB + ro + xo;
            f32x2 vL0 = {a[0],        q[0]};              // adjacent px -> ds_read2_b32
            f32x2 vL1 = {a[1],        q[1]};
            f32x2 vH0 = {a[PSTR],     q[PSTR]};
            f32x2 vH1 = {a[PSTR + 1], q[PSTR + 1]};
            f32x2 t = vL0 * hx + vL1 * lx;                // v_pk_fma_f32 candidates
            f32x2 u = vH0 * hx + vH1 * lx;
            acc += t * hy + u * ly;
        };
        quad(yg.x, hy0, ly0, xg.x, hx0, lx0);
        quad(yg.x, hy0, ly0, xg.z, hx1, lx1);
        quad(yg.z, hy1, ly1, xg.x, hx0, lx0);
        quad(yg.z, hy1, ly1, xg.z, hx1, lx1);
        acc *= 0.25f;                                     // / (SR*SR)

        float* ob = out + ((size_t)k * FEAT_C + cg * CPB + cp * 2) * NBINS + bin;
        ob[0]     = acc.x;
        ob[NBINS] = acc.y;
    }
}

extern "C" void kernel_launch(void* const* d_in, const int* in_sizes, int n_in,
                              void* d_out, int out_size, void* d_ws, size_t ws_size,
                              hipStream_t stream) {
    const float* feat = (const float*)d_in[0];
    const float* rois = (const float*)d_in[1];
    float*       outp = (float*)d_out;
    roialign_fwd<<<dim3(NROI * GROUPS), dim3(256), 0, stream>>>(feat, rois, outp);
}

// Round 4
// 104.623 us; speedup vs baseline: 1.4840x; 1.0072x over previous
//
#include <hip/hip_runtime.h>

// RoIAlign forward (SR=2, aligned). feat [4,256,100,100] f32, rois [512,5], out [512,256,7,7].
// Block = (roi, 8-channel group). Wave 0 computes sampling geometry into LDS;
// all waves stage the f32 source patch (float4 global -> b128 LDS, boundary
// rows/cols handled by address clamp + weight zeroing, NO fixup pass); 196
// threads then compute 2 channels x 49 bins each from LDS via ds_read2 pairs.

#define FEAT_C 256
#define FEAT_H 100
#define FEAT_W 100
#define HW     (FEAT_H * FEAT_W)
#define NROI   512
#define NBINS  49
#define CPB    8                      // channels per block
#define GROUPS 32                     // FEAT_C / CPB
#define SCALE  0.25f
#define PROWS  25                     // max rows: floor-span<=23 (+2)
#define PSTR   28                     // cols: 3(align) + 23 + 2, mult of 4
#define CSTR   (PSTR * PROWS)         // 700 dwords / channel

typedef float f32x2 __attribute__((ext_vector_type(2)));

// Matches ref: v = max(v,0); l = floor(v) clamped at cap; fr = v - l_clamped.
__device__ __forceinline__ void samp_geo(float s, float bsz, int idx, int sr_i,
                                         int& lo, float& fr) {
    float v = s + bsz * ((float)idx + ((float)sr_i + 0.5f) * 0.5f);
    v = fmaxf(v, 0.0f);
    int l = (int)v;
    if (l > FEAT_H - 1) l = FEAT_H - 1;   // H == W == 100
    fr = v - (float)l;
    lo = l;
}

__global__ __launch_bounds__(256) void roialign_fwd(
    const float* __restrict__ feat,
    const float* __restrict__ rois,
    float* __restrict__ out)
{
    __shared__ __align__(16) float s_patch[CPB * CSTR];   // 22400 B
    __shared__ __align__(16) int2  s_yg[14];              // {(yl-y0)*PSTR, bits(ly)}
    __shared__ __align__(16) int2  s_xg[14];              // {xl-ax0, bits(lx')}
    __shared__ __align__(16) int   s_meta[8];             // b, y0, ax0, rows, aspan

    const int bid = blockIdx.x;
    const int k   = bid >> 5;
    const int cg  = bid & (GROUPS - 1);
    const int tid = threadIdx.x;

    // ---- Geometry: wave 0 only ----
    if (tid < 32) {
        const float* r = rois + k * 5;                    // uniform -> s_loads
        if (tid == 28) s_meta[0] = (int)r[0];
        if (tid < 28) {
            const bool isy = tid < 14;
            const int  t   = isy ? tid : tid - 14;
            float s   = (isy ? r[2] : r[1]) * SCALE - 0.5f;
            float e   = (isy ? r[4] : r[3]) * SCALE - 0.5f;
            float bsz = (e - s) * (1.0f / 7.0f);
            int lo; float fr;
            samp_geo(s, bsz, t >> 1, t & 1, lo, fr);
            int o0; float fd;
            samp_geo(s, bsz, 0, 0, o0, fd);               // y0 / x0 (bit-identical)
            if (isy) {
                s_yg[t] = make_int2((lo - o0) * PSTR, __float_as_int(fr));
                if (t == 13) { s_meta[1] = o0; s_meta[3] = lo - o0 + 2; }  // y0, rows
            } else {
                int a0 = o0 & ~3;                         // 16B-aligned x origin
                if (lo >= FEAT_W - 1) fr = 0.0f;          // xh==xl at border: kill weight
                s_xg[t] = make_int2(lo - a0, __float_as_int(fr));
                if (t == 13) { s_meta[2] = a0; s_meta[4] = lo - a0 + 2; }  // ax0, aspan
            }
        }
    }
    __syncthreads();

    // ---- Stage patch: py = tid/7, q = tid%7 (7 quads cover PSTR=28) ----
    {
        const int4 m     = *reinterpret_cast<const int4*>(s_meta);  // b,y0,ax0,rows
        const int  aspan = s_meta[4];
        const int  py    = (tid * 9363) >> 16;            // tid/7 exact for tid<256
        const int  q     = tid - py * 7;
        if (py < m.w && q * 4 < aspan) {
            int qs = m.z + q * 4;
            if (qs > FEAT_W - 4) qs = FEAT_W - 4;         // clamped quads only feed
            int sy = m.y + py;                            //  zero-weight/unused cells
            if (sy > FEAT_H - 1) sy = FEAT_H - 1;         // bottom-row duplication
            const float* src = feat + ((size_t)(m.x * FEAT_C) + cg * CPB) * HW
                             + sy * FEAT_W + qs;
            float* dst = s_patch + py * PSTR + q * 4;
            #pragma unroll
            for (int c = 0; c < CPB; c++)
                *reinterpret_cast<float4*>(dst + c * CSTR) =
                    *reinterpret_cast<const float4*>(src + c * HW);
        }
    }
    __syncthreads();

    // ---- Compute: 196 threads, 2 channels x 1 bin each ----
    if (tid < 4 * NBINS) {
        const int cp  = (tid * 335) >> 14;                // tid/49 exact for tid<196
        const int bin = tid - cp * NBINS;
        const int ph  = (bin * 37) >> 8;                  // bin/7 exact for bin<49
        const int pw  = bin - ph * 7;

        const int4 yg = *reinterpret_cast<const int4*>(&s_yg[2 * ph]);
        const int4 xg = *reinterpret_cast<const int4*>(&s_xg[2 * pw]);
        const float* pA = s_patch + (cp * 2) * CSTR;
        const float* pB = pA + CSTR;

        const float ly0 = __int_as_float(yg.y), hy0 = 1.0f - ly0;
        const float ly1 = __int_as_float(yg.w), hy1 = 1.0f - ly1;
        const float lx0 = __int_as_float(xg.y), hx0 = 1.0f - lx0;
        const float lx1 = __int_as_float(xg.w), hx1 = 1.0f - lx1;

        f32x2 acc = {0.0f, 0.0f};
        auto quad = [&](int ro, float hy, float ly, int xo, float hx, float lx) {
            const float* a = pA + ro + xo;
            const float* q = pB + ro + xo;
            f32x2 vL0 = {a[0],        q[0]};              // (0,1) & (28,29) dword
            f32x2 vL1 = {a[1],        q[1]};              //  offsets -> ds_read2_b32
            f32x2 vH0 = {a[PSTR],     q[PSTR]};
            f32x2 vH1 = {a[PSTR + 1], q[PSTR + 1]};
            f32x2 t = vL0 * hx + vL1 * lx;
            f32x2 u = vH0 * hx + vH1 * lx;
            acc += t * hy + u * ly;
        };
        quad(yg.x, hy0, ly0, xg.x, hx0, lx0);
        quad(yg.x, hy0, ly0, xg.z, hx1, lx1);
        quad(yg.z, hy1, ly1, xg.x, hx0, lx0);
        quad(yg.z, hy1, ly1, xg.z, hx1, lx1);
        acc *= 0.25f;                                     // / (SR*SR)

        float* ob = out + ((size_t)k * FEAT_C + cg * CPB + cp * 2) * NBINS + bin;
        ob[0]     = acc.x;
        ob[NBINS] = acc.y;
    }
}

extern "C" void kernel_launch(void* const* d_in, const int* in_sizes, int n_in,
                              void* d_out, int out_size, void* d_ws, size_t ws_size,
                              hipStream_t stream) {
    const float* feat = (const float*)d_in[0];
    const float* rois = (const float*)d_in[1];
    float*       outp = (float*)d_out;
    roialign_fwd<<<dim3(NROI * GROUPS), dim3(256), 0, stream>>>(feat, rois, outp);
}